// Round 6
// baseline (407.106 us; speedup 1.0000x reference)
//
#include <hip/hip_runtime.h>
#include <hip/hip_fp16.h>

#define FD 128    // hidden feature dim
#define OD 64     // output dim
#define KC 32     // privatized histogram copies for deg_out
#define RB 64     // nodes per bucket (dst >> 6)
#define CHUNKS 256
#define PSUB 8    // partition sub-blocks per chunk (grid = CHUNKS*PSUB)
#define NBMAX 1024

// ---------------- misc ----------------

__global__ void zero_kernel(int* __restrict__ a, int n) {
    int i = blockIdx.x * 256 + threadIdx.x;
    if (i < n) a[i] = 0;
}

__global__ void rout_kernel(const int* __restrict__ cnt, float* __restrict__ r_out, int N) {
    int v = blockIdx.x * 256 + threadIdx.x;
    if (v >= N) return;
    int s = 0;
    #pragma unroll
    for (int k = 0; k < KC; k++) s += cnt[k * N + v];
    r_out[v] = rsqrtf((float)max(s, 1));
}

// Xs(half) = r_out (row) * X ; one float4 -> 4 halves per thread
__global__ void prescale_kernel(const float* __restrict__ X, const float* __restrict__ r_out,
                                __half* __restrict__ Xs, int n4) {
    int i = blockIdx.x * 256 + threadIdx.x;
    if (i >= n4) return;
    int v = i >> 5;                    // 32 float4 per 128-float row
    float r = r_out[v];
    float4 t = ((const float4*)X)[i];
    __half2 h0 = __floats2half2_rn(t.x * r, t.y * r);
    __half2 h1 = __floats2half2_rn(t.z * r, t.w * r);
    ((__half2*)Xs)[2 * i]     = h0;
    ((__half2*)Xs)[2 * i + 1] = h1;
}

// ---------------- coarse bucket partition (counting sort) ----------------

__global__ __launch_bounds__(256) void bucket_hist_kernel(const int* __restrict__ dst,
                                                          int* __restrict__ hist_g,
                                                          int E, int NB, int CS) {
    __shared__ int hist[NBMAX];
    int c = blockIdx.x;
    for (int t = threadIdx.x; t < NB; t += 256) hist[t] = 0;
    __syncthreads();
    int e1 = min(c * CS + CS, E);
    for (int e = c * CS + threadIdx.x; e < e1; e += 256)
        atomicAdd(&hist[dst[e] >> 6], 1);
    __syncthreads();
    for (int t = threadIdx.x; t < NB; t += 256) hist_g[c * NB + t] = hist[t];
}

__global__ __launch_bounds__(1024) void bucket_scan_kernel(const int* __restrict__ hist_g,
                                                           int* __restrict__ bstart,
                                                           int NB, int E) {
    __shared__ int wsum[16];
    int tid = threadIdx.x, lane = tid & 63, w = tid >> 6;
    int total = 0;
    if (tid < NB)
        for (int c = 0; c < CHUNKS; c++) total += hist_g[c * NB + tid];
    int x = total;
    #pragma unroll
    for (int d = 1; d < 64; d <<= 1) {
        int t = __shfl_up(x, d, 64);
        if (lane >= d) x += t;
    }
    if (lane == 63) wsum[w] = x;
    __syncthreads();
    if (w == 0) {
        int s = (lane < 16) ? wsum[lane] : 0;
        #pragma unroll
        for (int d = 1; d < 16; d <<= 1) {
            int t = __shfl_up(s, d, 64);
            if (lane >= d) s += t;
        }
        if (lane < 16) wsum[lane] = s;
    }
    __syncthreads();
    int off = (w == 0) ? 0 : wsum[w - 1];
    if (tid < NB) bstart[tid] = x + off - total;
    if (tid == 0) bstart[NB] = E;
}

__global__ void bucket_cursor_kernel(const int* __restrict__ hist_g, const int* __restrict__ bstart,
                                     int* __restrict__ cursor, int NB) {
    int b = blockIdx.x * 256 + threadIdx.x;
    if (b >= NB) return;
    int run = bstart[b];
    for (int c = 0; c < CHUNKS; c++) {
        cursor[c * NB + b] = run;
        run += hist_g[c * NB + b];
    }
}

// scatter packed edges (dl<<17 | src) into bucket runs. PSUB blocks share one
// chunk's cursor row via global atomics (contention per address ~= seg len ~8).
// Fused: privatized src histogram (deg_out); k = blockIdx % KC.
__global__ __launch_bounds__(256) void partition_kernel(const int* __restrict__ src,
                                                        const int* __restrict__ dst,
                                                        int* __restrict__ cursor,
                                                        int* __restrict__ epack,
                                                        int* __restrict__ cnt_src,
                                                        int E, int NB, int CS, int N) {
    int bb = blockIdx.x;
    int c = bb >> 3;                       // chunk (PSUB=8)
    int sub = bb & 7;
    int k = bb & (KC - 1);
    int* curc = cursor + c * NB;
    int e1 = min(c * CS + CS, E);
    for (int e = c * CS + sub * 256 + threadIdx.x; e < e1; e += 256 * PSUB) {
        int d = dst[e];
        int s = src[e];
        int pos = atomicAdd(&curc[d >> 6], 1);
        epack[pos] = ((d & 63) << 17) | s;   // src < 2^17
        atomicAdd(&cnt_src[k * N + s], 1);
    }
}

// per-bucket LDS counting sort -> exact per-node CSR (csrc) + row_start + r_in
__global__ __launch_bounds__(256) void bucket_sort_kernel(const int* __restrict__ epack,
                                                          const int* __restrict__ bstart,
                                                          int* __restrict__ csrc,
                                                          int* __restrict__ row_start,
                                                          float* __restrict__ r_in,
                                                          int N, int NB, int E) {
    __shared__ int cnt[RB];
    __shared__ int cur[RB];
    int b = blockIdx.x, tid = threadIdx.x;
    int s0 = bstart[b], s1 = bstart[b + 1];
    if (tid < RB) cnt[tid] = 0;
    __syncthreads();
    for (int e = s0 + tid; e < s1; e += 256)
        atomicAdd(&cnt[epack[e] >> 17], 1);
    __syncthreads();
    if (tid < RB) {
        int c = cnt[tid];
        int x = c;
        #pragma unroll
        for (int d = 1; d < 64; d <<= 1) {
            int t = __shfl_up(x, d, 64);
            if (tid >= d) x += t;
        }
        int start = s0 + x - c;            // exclusive
        cur[tid] = start;
        int node = b * RB + tid;
        if (node < N) {
            row_start[node] = start;
            r_in[node] = rsqrtf((float)max(c, 1));
        }
    }
    if (b == NB - 1 && tid == 0) row_start[N] = E;
    __syncthreads();
    for (int e = s0 + tid; e < s1; e += 256) {
        int pk = epack[e];
        int pos = atomicAdd(&cur[pk >> 17], 1);
        csrc[pos] = pk & 0x1FFFF;
    }
}

// ---------------- aggregation: one wave per node, CSR gather (fp16 rows) ----------------
__global__ __launch_bounds__(256) void agg128_kernel(const __half* __restrict__ Xs,
                                                     const float* __restrict__ r_in,
                                                     const int* __restrict__ rs,
                                                     const int* __restrict__ csrc,
                                                     float* __restrict__ Z, int N) {
    const int lane = threadIdx.x & 63, wv = threadIdx.x >> 6;
    int v = blockIdx.x * 4 + wv;
    if (v >= N) return;
    int s0 = rs[v], s1 = rs[v + 1];
    float ax = 0.f, ay = 0.f;
    int e = s0;
    for (; e + 8 <= s1; e += 8) {
        int idx[8];
        #pragma unroll
        for (int u = 0; u < 8; u++) idx[u] = csrc[e + u];
        __half2 t[8];
        #pragma unroll
        for (int u = 0; u < 8; u++)
            t[u] = ((const __half2*)(Xs + (size_t)idx[u] * FD))[lane];
        #pragma unroll
        for (int u = 0; u < 8; u++) {
            float2 f = __half22float2(t[u]);
            ax += f.x; ay += f.y;
        }
    }
    for (; e < s1; e++) {
        float2 f = __half22float2(((const __half2*)(Xs + (size_t)csrc[e] * FD))[lane]);
        ax += f.x; ay += f.y;
    }
    float ri = r_in[v];
    float2 o; o.x = ax * ri; o.y = ay * ri;
    ((float2*)(Z + (size_t)v * FD))[lane] = o;
}

__global__ __launch_bounds__(256) void agg64_kernel(const __half* __restrict__ T,
                                                    const float* __restrict__ r_in,
                                                    const int* __restrict__ rs,
                                                    const int* __restrict__ csrc,
                                                    const float* __restrict__ bc,
                                                    float* __restrict__ out, int N) {
    const int lane = threadIdx.x & 63, wv = threadIdx.x >> 6;
    int v = blockIdx.x * 4 + wv;
    if (v >= N) return;
    int s0 = rs[v], s1 = rs[v + 1];
    float a = 0.f;
    int e = s0;
    for (; e + 8 <= s1; e += 8) {
        int idx[8];
        #pragma unroll
        for (int u = 0; u < 8; u++) idx[u] = csrc[e + u];
        __half t[8];
        #pragma unroll
        for (int u = 0; u < 8; u++) t[u] = T[(size_t)idx[u] * OD + lane];
        #pragma unroll
        for (int u = 0; u < 8; u++) a += __half2float(t[u]);
    }
    for (; e < s1; e++) a += __half2float(T[(size_t)csrc[e] * OD + lane]);
    out[(size_t)v * OD + lane] = a * r_in[v] + bc[lane];
}

// ---------------- fused GEMM: tbuf(Mx64,fp16) = (relu(A@W1+b1)*r_out) @ Wc ----------------
__global__ __launch_bounds__(256) void gemm_fused_kernel(const float* __restrict__ A,
                                                         const float* __restrict__ W1,
                                                         const float* __restrict__ b1,
                                                         const float* __restrict__ rowscale,
                                                         const float* __restrict__ Wc,
                                                         __half* __restrict__ C, int M) {
    __shared__ float As[8][128];
    __shared__ float Bs[8][128];
    __shared__ __half Ys[128][130];   // padded: bank spread for row-strided reads
    __shared__ float Wcs[128][64];
    const int tid = threadIdx.x;
    const int blk0 = blockIdx.x * 128;
    const int tr = tid >> 4;        // 0..15
    const int tc = tid & 15;        // 0..15

    // stage Wc (used only after the phase-boundary barrier)
    for (int idx = tid; idx < 128 * 64; idx += 256)
        Wcs[idx >> 6][idx & 63] = Wc[idx];

    float acc[8][8];
    #pragma unroll
    for (int i = 0; i < 8; i++)
        #pragma unroll
        for (int j = 0; j < 8; j++) acc[i][j] = 0.f;

    const int lm = tid >> 1;
    const int lka = (tid & 1) * 4;
    const int arow = blk0 + lm;
    const int lkb = tid >> 5;                 // 0..7
    const int lnb = (tid & 31) * 4;           // 0..124

    for (int k0 = 0; k0 < 128; k0 += 8) {
        float4 av = make_float4(0.f, 0.f, 0.f, 0.f);
        if (arow < M) av = *(const float4*)(A + (size_t)arow * 128 + k0 + lka);
        float4 bv = *(const float4*)(W1 + (size_t)(k0 + lkb) * 128 + lnb);
        __syncthreads();
        As[lka + 0][lm] = av.x;
        As[lka + 1][lm] = av.y;
        As[lka + 2][lm] = av.z;
        As[lka + 3][lm] = av.w;
        *(float4*)&Bs[lkb][lnb] = bv;
        __syncthreads();
        #pragma unroll
        for (int kk = 0; kk < 8; kk++) {
            float a[8], bb[8];
            #pragma unroll
            for (int i = 0; i < 8; i++) a[i] = As[kk][tr * 8 + i];
            #pragma unroll
            for (int j = 0; j < 8; j++) bb[j] = Bs[kk][tc * 8 + j];
            #pragma unroll
            for (int i = 0; i < 8; i++)
                #pragma unroll
                for (int j = 0; j < 8; j++) acc[i][j] += a[i] * bb[j];
        }
    }

    // epilogue 1: y = relu(acc + b1)*r_out -> Ys (fp16)
    #pragma unroll
    for (int i = 0; i < 8; i++) {
        int row = blk0 + tr * 8 + i;
        float rsc = (row < M) ? rowscale[row] : 0.f;
        #pragma unroll
        for (int j = 0; j < 8; j += 2) {
            float v0 = fmaxf(acc[i][j]     + b1[tc * 8 + j],     0.f) * rsc;
            float v1 = fmaxf(acc[i][j + 1] + b1[tc * 8 + j + 1], 0.f) * rsc;
            *(__half2*)&Ys[tr * 8 + i][tc * 8 + j] = __floats2half2_rn(v0, v1);
        }
    }
    __syncthreads();

    // phase 2: tbuf = Ys @ Wcs  (each thread: 8 rows x 4 cols)
    float acc2[8][4];
    #pragma unroll
    for (int i = 0; i < 8; i++)
        #pragma unroll
        for (int j = 0; j < 4; j++) acc2[i][j] = 0.f;

    for (int k = 0; k < 128; k += 2) {
        float2 a2[8];
        #pragma unroll
        for (int i = 0; i < 8; i++)
            a2[i] = __half22float2(*(const __half2*)&Ys[tr * 8 + i][k]);
        float4 b0 = *(const float4*)&Wcs[k][tc * 4];
        float4 b1v = *(const float4*)&Wcs[k + 1][tc * 4];
        #pragma unroll
        for (int i = 0; i < 8; i++) {
            acc2[i][0] += a2[i].x * b0.x + a2[i].y * b1v.x;
            acc2[i][1] += a2[i].x * b0.y + a2[i].y * b1v.y;
            acc2[i][2] += a2[i].x * b0.z + a2[i].y * b1v.z;
            acc2[i][3] += a2[i].x * b0.w + a2[i].y * b1v.w;
        }
    }

    #pragma unroll
    for (int i = 0; i < 8; i++) {
        int row = blk0 + tr * 8 + i;
        if (row < M) {
            *(__half2*)&C[(size_t)row * OD + tc * 4]     = __floats2half2_rn(acc2[i][0], acc2[i][1]);
            *(__half2*)&C[(size_t)row * OD + tc * 4 + 2] = __floats2half2_rn(acc2[i][2], acc2[i][3]);
        }
    }
}

// ---------------- fold W2@Wf, b2@Wf+bf ----------------
__global__ void fold_kernel(const float* __restrict__ W2, const float* __restrict__ Wf,
                            const float* __restrict__ b2, const float* __restrict__ bf,
                            float* __restrict__ Wc, float* __restrict__ bc) {
    int idx = blockIdx.x * 256 + threadIdx.x;
    if (idx < FD * OD) {
        int i = idx / OD, j = idx % OD;
        float s = 0.f;
        for (int k = 0; k < FD; k++) s += W2[i * FD + k] * Wf[k * OD + j];
        Wc[idx] = s;
    }
    if (idx < OD) {
        float s = bf[idx];
        for (int k = 0; k < FD; k++) s += b2[k] * Wf[k * OD + idx];
        bc[idx] = s;
    }
}

// ---------------- launch ----------------
extern "C" void kernel_launch(void* const* d_in, const int* in_sizes, int n_in,
                              void* d_out, int out_size, void* d_ws, size_t ws_size,
                              hipStream_t stream) {
    const float* in_feat = (const float*)d_in[0];
    const int*   src     = (const int*)d_in[1];
    const int*   dst     = (const int*)d_in[2];
    const float* W1      = (const float*)d_in[3];
    const float* b1      = (const float*)d_in[4];
    const float* W2      = (const float*)d_in[5];
    const float* b2      = (const float*)d_in[6];
    const float* Wf      = (const float*)d_in[7];
    const float* bf      = (const float*)d_in[8];
    float* out = (float*)d_out;

    const int N = in_sizes[0] / FD;        // 50000
    const int E = in_sizes[1];             // 1600000
    const int NB = (N + RB - 1) / RB;      // 782 (<= NBMAX)
    const int CS = (E + CHUNKS - 1) / CHUNKS;

    char* ws = (char*)d_ws;
    size_t off = 0;
    auto alloc = [&](size_t bytes) -> void* {
        void* p = ws + off;
        off += (bytes + 255) / 256 * 256;
        return p;
    };
    // cnt_out (6.4 MB) dead after rout; tbuf (N*OD*2 = 6.4 MB half) aliases it.
    int*    cnt_out = (int*)alloc((size_t)KC * N * 4);
    __half* tbuf    = (__half*)cnt_out;
    int*    epack   = (int*)alloc((size_t)E * 4);        // dead after bucket_sort
    float*  r_out   = (float*)alloc((size_t)N * 4);
    float*  r_in    = (float*)alloc((size_t)N * 4);
    int*    hist_g  = (int*)alloc((size_t)CHUNKS * NB * 4);
    int*    cursor  = (int*)alloc((size_t)CHUNKS * NB * 4);
    int*    bstart  = (int*)alloc((size_t)(NB + 1) * 4);
    int*    csrc    = (int*)alloc((size_t)E * 4);
    int*    row_start = (int*)alloc((size_t)(N + 1) * 4);
    float*  z1      = (float*)alloc((size_t)N * FD * 4);
    __half* Xs      = (__half*)alloc((size_t)N * FD * 2);
    float*  Wc      = (float*)alloc((size_t)FD * OD * 4);
    float*  bc      = (float*)alloc((size_t)OD * 4);
    (void)ws_size; (void)n_in; (void)out_size;

    const int gN = (N + 255) / 256;

    // exact dst-sort: coarse bucket partition + per-bucket LDS counting sort.
    // partition also builds the privatized src histogram (deg_out).
    zero_kernel<<<(KC * N + 255) / 256, 256, 0, stream>>>(cnt_out, KC * N);
    bucket_hist_kernel<<<CHUNKS, 256, 0, stream>>>(dst, hist_g, E, NB, CS);
    bucket_scan_kernel<<<1, 1024, 0, stream>>>(hist_g, bstart, NB, E);
    bucket_cursor_kernel<<<(NB + 255) / 256, 256, 0, stream>>>(hist_g, bstart, cursor, NB);
    partition_kernel<<<CHUNKS * PSUB, 256, 0, stream>>>(src, dst, cursor, epack, cnt_out, E, NB, CS, N);
    bucket_sort_kernel<<<NB, 256, 0, stream>>>(epack, bstart, csrc, row_start, r_in, N, NB, E);
    rout_kernel<<<gN, 256, 0, stream>>>(cnt_out, r_out, N);

    // fold final two linear layers
    fold_kernel<<<(FD * OD + 255) / 256, 256, 0, stream>>>(W2, Wf, b2, bf, Wc, bc);

    // layer 1: Xs = half(r_out*x) ; z1 = r_in*Agg(Xs)
    prescale_kernel<<<(N * 32 + 255) / 256, 256, 0, stream>>>(in_feat, r_out, Xs, N * 32);
    agg128_kernel<<<(N + 3) / 4, 256, 0, stream>>>(Xs, r_in, row_start, csrc, z1, N);

    // fused: tbuf = half( (relu(z1@W1+b1)*r_out) @ Wc )
    gemm_fused_kernel<<<(N + 127) / 128, 256, 0, stream>>>(z1, W1, b1, r_out, Wc, tbuf, N);

    // final: out = r_in*Agg(tbuf) + bc
    agg64_kernel<<<(N + 3) / 4, 256, 0, stream>>>(tbuf, r_in, row_start, csrc, bc, out, N);
}

// Round 7
// 359.541 us; speedup vs baseline: 1.1323x; 1.1323x over previous
//
#include <hip/hip_runtime.h>
#include <hip/hip_fp16.h>

#define FD 128    // hidden feature dim
#define OD 64     // output dim
#define KC 32     // privatized histogram copies for deg_out
#define RN 256    // nodes per region (dst >> 8)
#define CHUNKS 256
#define NRMAX 1024

// ---------------- misc ----------------

__global__ void zero_kernel(int* __restrict__ a, int n) {
    int i = blockIdx.x * 256 + threadIdx.x;
    if (i < n) a[i] = 0;
}

__global__ void rout_kernel(const int* __restrict__ cnt, float* __restrict__ r_out, int N) {
    int v = blockIdx.x * 256 + threadIdx.x;
    if (v >= N) return;
    int s = 0;
    #pragma unroll
    for (int k = 0; k < KC; k++) s += cnt[k * N + v];
    r_out[v] = rsqrtf((float)max(s, 1));
}

// Xs(half) = r_out (row) * X ; one float4 -> 4 halves per thread
__global__ void prescale_kernel(const float* __restrict__ X, const float* __restrict__ r_out,
                                __half* __restrict__ Xs, int n4) {
    int i = blockIdx.x * 256 + threadIdx.x;
    if (i >= n4) return;
    int v = i >> 5;                    // 32 float4 per 128-float row
    float r = r_out[v];
    float4 t = ((const float4*)X)[i];
    __half2 h0 = __floats2half2_rn(t.x * r, t.y * r);
    __half2 h1 = __floats2half2_rn(t.z * r, t.w * r);
    ((__half2*)Xs)[2 * i]     = h0;
    ((__half2*)Xs)[2 * i + 1] = h1;
}

// ---------------- pass 1: partition edges by region (dst>>8) ----------------

__global__ __launch_bounds__(256) void region_hist_kernel(const int* __restrict__ dst,
                                                          int* __restrict__ hist_g,
                                                          int E, int NR, int CS) {
    __shared__ int hist[NRMAX];
    int c = blockIdx.x;
    for (int t = threadIdx.x; t < NR; t += 256) hist[t] = 0;
    __syncthreads();
    int e1 = min(c * CS + CS, E);
    for (int e = c * CS + threadIdx.x; e < e1; e += 256)
        atomicAdd(&hist[dst[e] >> 8], 1);
    __syncthreads();
    for (int t = threadIdx.x; t < NR; t += 256) hist_g[c * NR + t] = hist[t];
}

__global__ __launch_bounds__(1024) void region_scan_kernel(const int* __restrict__ hist_g,
                                                           int* __restrict__ rstart,
                                                           int NR, int E) {
    __shared__ int wsum[16];
    int tid = threadIdx.x, lane = tid & 63, w = tid >> 6;
    int total = 0;
    if (tid < NR)
        for (int c = 0; c < CHUNKS; c++) total += hist_g[c * NR + tid];
    int x = total;
    #pragma unroll
    for (int d = 1; d < 64; d <<= 1) {
        int t = __shfl_up(x, d, 64);
        if (lane >= d) x += t;
    }
    if (lane == 63) wsum[w] = x;
    __syncthreads();
    if (w == 0) {
        int s = (lane < 16) ? wsum[lane] : 0;
        #pragma unroll
        for (int d = 1; d < 16; d <<= 1) {
            int t = __shfl_up(s, d, 64);
            if (lane >= d) s += t;
        }
        if (lane < 16) wsum[lane] = s;
    }
    __syncthreads();
    int off = (w == 0) ? 0 : wsum[w - 1];
    if (tid < NR) rstart[tid] = x + off - total;
    if (tid == 0) rstart[NR] = E;
}

__global__ void region_cursor_kernel(const int* __restrict__ hist_g, const int* __restrict__ rstart,
                                     int* __restrict__ cursor, int NR) {
    int b = blockIdx.x * 256 + threadIdx.x;
    if (b >= NR) return;
    int run = rstart[b];
    for (int c = 0; c < CHUNKS; c++) {
        cursor[c * NR + b] = run;
        run += hist_g[c * NR + b];
    }
}

// scatter packed edges ((dst&255)<<17 | src) into region runs via LDS cursors.
// Run length per (chunk,region) ~ E/(CHUNKS*NR) ~ 32 ints = 128 B (full lines).
// Fused: KC-privatized src histogram (deg_out).
__global__ __launch_bounds__(512) void partition_kernel(const int* __restrict__ src,
                                                        const int* __restrict__ dst,
                                                        const int* __restrict__ cursor,
                                                        int* __restrict__ epack,
                                                        int* __restrict__ cnt_src,
                                                        int E, int NR, int CS, int N) {
    __shared__ int cur[NRMAX];
    int c = blockIdx.x;
    int k = blockIdx.x & (KC - 1);
    for (int t = threadIdx.x; t < NR; t += 512) cur[t] = cursor[c * NR + t];
    __syncthreads();
    int e1 = min(c * CS + CS, E);
    for (int e = c * CS + threadIdx.x; e < e1; e += 512) {
        int d = dst[e];
        int s = src[e];
        int pos = atomicAdd(&cur[d >> 8], 1);
        epack[pos] = ((d & 255) << 17) | s;   // src < 2^17
        atomicAdd(&cnt_src[k * N + s], 1);
    }
}

// ---------------- pass 2: per-region LDS counting sort -> exact CSR ----------------
// One block per region (256 nodes, ~8K edges). Writes stay in the region's
// contiguous window of csrc (32 KB) -> full-line locality.
__global__ __launch_bounds__(1024) void region_sort_kernel(const int* __restrict__ epack,
                                                           const int* __restrict__ rstart,
                                                           int* __restrict__ csrc,
                                                           int* __restrict__ row_start,
                                                           float* __restrict__ r_in,
                                                           int N, int NR, int E) {
    __shared__ int cnt[RN];
    __shared__ int cur[RN];
    __shared__ int wsum[16];
    const int r = blockIdx.x, tid = threadIdx.x;
    const int lane = tid & 63, w = tid >> 6;
    const int s0 = rstart[r], s1 = rstart[r + 1];
    if (tid < RN) cnt[tid] = 0;
    __syncthreads();
    for (int e = s0 + tid; e < s1; e += 1024)
        atomicAdd(&cnt[epack[e] >> 17], 1);
    __syncthreads();
    // scan the 256 counters (threads 0..255 = 4 waves)
    int cv = (tid < RN) ? cnt[tid] : 0;
    int x = cv;
    #pragma unroll
    for (int d = 1; d < 64; d <<= 1) {
        int t = __shfl_up(x, d, 64);
        if (lane >= d) x += t;
    }
    if (lane == 63 && w < 4) wsum[w] = x;
    __syncthreads();
    if (tid < RN) {
        int woff = 0;
        for (int i = 0; i < w; i++) woff += wsum[i];
        int excl = x - cv + woff;
        int start = s0 + excl;
        cur[tid] = start;
        int node = r * RN + tid;
        if (node < N) {
            row_start[node] = start;
            r_in[node] = rsqrtf((float)max(cv, 1));
        }
    }
    if (r == NR - 1 && tid == 0) row_start[N] = E;
    __syncthreads();
    for (int e = s0 + tid; e < s1; e += 1024) {
        int pk = epack[e];
        int pos = atomicAdd(&cur[pk >> 17], 1);
        csrc[pos] = pk & 0x1FFFF;
    }
}

// ---------------- aggregation: one wave per node, CSR gather (fp16 rows) ----------------
__global__ __launch_bounds__(256) void agg128_kernel(const __half* __restrict__ Xs,
                                                     const float* __restrict__ r_in,
                                                     const int* __restrict__ rs,
                                                     const int* __restrict__ csrc,
                                                     float* __restrict__ Z, int N) {
    const int lane = threadIdx.x & 63, wv = threadIdx.x >> 6;
    int v = blockIdx.x * 4 + wv;
    if (v >= N) return;
    int s0 = rs[v], s1 = rs[v + 1];
    float ax = 0.f, ay = 0.f;
    int e = s0;
    for (; e + 8 <= s1; e += 8) {
        int idx[8];
        #pragma unroll
        for (int u = 0; u < 8; u++) idx[u] = csrc[e + u];
        __half2 t[8];
        #pragma unroll
        for (int u = 0; u < 8; u++)
            t[u] = ((const __half2*)(Xs + (size_t)idx[u] * FD))[lane];
        #pragma unroll
        for (int u = 0; u < 8; u++) {
            float2 f = __half22float2(t[u]);
            ax += f.x; ay += f.y;
        }
    }
    for (; e < s1; e++) {
        float2 f = __half22float2(((const __half2*)(Xs + (size_t)csrc[e] * FD))[lane]);
        ax += f.x; ay += f.y;
    }
    float ri = r_in[v];
    float2 o; o.x = ax * ri; o.y = ay * ri;
    ((float2*)(Z + (size_t)v * FD))[lane] = o;
}

__global__ __launch_bounds__(256) void agg64_kernel(const __half* __restrict__ T,
                                                    const float* __restrict__ r_in,
                                                    const int* __restrict__ rs,
                                                    const int* __restrict__ csrc,
                                                    const float* __restrict__ bc,
                                                    float* __restrict__ out, int N) {
    const int lane = threadIdx.x & 63, wv = threadIdx.x >> 6;
    int v = blockIdx.x * 4 + wv;
    if (v >= N) return;
    int s0 = rs[v], s1 = rs[v + 1];
    float a = 0.f;
    int e = s0;
    for (; e + 8 <= s1; e += 8) {
        int idx[8];
        #pragma unroll
        for (int u = 0; u < 8; u++) idx[u] = csrc[e + u];
        __half t[8];
        #pragma unroll
        for (int u = 0; u < 8; u++) t[u] = T[(size_t)idx[u] * OD + lane];
        #pragma unroll
        for (int u = 0; u < 8; u++) a += __half2float(t[u]);
    }
    for (; e < s1; e++) a += __half2float(T[(size_t)csrc[e] * OD + lane]);
    out[(size_t)v * OD + lane] = a * r_in[v] + bc[lane];
}

// ---------------- fused GEMM: tbuf(Mx64,fp16) = (relu(A@W1+b1)*r_out) @ Wc ----------------
__global__ __launch_bounds__(256) void gemm_fused_kernel(const float* __restrict__ A,
                                                         const float* __restrict__ W1,
                                                         const float* __restrict__ b1,
                                                         const float* __restrict__ rowscale,
                                                         const float* __restrict__ Wc,
                                                         __half* __restrict__ C, int M) {
    __shared__ float As[8][128];
    __shared__ float Bs[8][128];
    __shared__ __half Ys[128][130];   // padded: bank spread for row-strided reads
    __shared__ float Wcs[128][64];
    const int tid = threadIdx.x;
    const int blk0 = blockIdx.x * 128;
    const int tr = tid >> 4;        // 0..15
    const int tc = tid & 15;        // 0..15

    // stage Wc (used only after the phase-boundary barrier)
    for (int idx = tid; idx < 128 * 64; idx += 256)
        Wcs[idx >> 6][idx & 63] = Wc[idx];

    float acc[8][8];
    #pragma unroll
    for (int i = 0; i < 8; i++)
        #pragma unroll
        for (int j = 0; j < 8; j++) acc[i][j] = 0.f;

    const int lm = tid >> 1;
    const int lka = (tid & 1) * 4;
    const int arow = blk0 + lm;
    const int lkb = tid >> 5;                 // 0..7
    const int lnb = (tid & 31) * 4;           // 0..124

    for (int k0 = 0; k0 < 128; k0 += 8) {
        float4 av = make_float4(0.f, 0.f, 0.f, 0.f);
        if (arow < M) av = *(const float4*)(A + (size_t)arow * 128 + k0 + lka);
        float4 bv = *(const float4*)(W1 + (size_t)(k0 + lkb) * 128 + lnb);
        __syncthreads();
        As[lka + 0][lm] = av.x;
        As[lka + 1][lm] = av.y;
        As[lka + 2][lm] = av.z;
        As[lka + 3][lm] = av.w;
        *(float4*)&Bs[lkb][lnb] = bv;
        __syncthreads();
        #pragma unroll
        for (int kk = 0; kk < 8; kk++) {
            float a[8], bb[8];
            #pragma unroll
            for (int i = 0; i < 8; i++) a[i] = As[kk][tr * 8 + i];
            #pragma unroll
            for (int j = 0; j < 8; j++) bb[j] = Bs[kk][tc * 8 + j];
            #pragma unroll
            for (int i = 0; i < 8; i++)
                #pragma unroll
                for (int j = 0; j < 8; j++) acc[i][j] += a[i] * bb[j];
        }
    }

    // epilogue 1: y = relu(acc + b1)*r_out -> Ys (fp16)
    #pragma unroll
    for (int i = 0; i < 8; i++) {
        int row = blk0 + tr * 8 + i;
        float rsc = (row < M) ? rowscale[row] : 0.f;
        #pragma unroll
        for (int j = 0; j < 8; j += 2) {
            float v0 = fmaxf(acc[i][j]     + b1[tc * 8 + j],     0.f) * rsc;
            float v1 = fmaxf(acc[i][j + 1] + b1[tc * 8 + j + 1], 0.f) * rsc;
            *(__half2*)&Ys[tr * 8 + i][tc * 8 + j] = __floats2half2_rn(v0, v1);
        }
    }
    __syncthreads();

    // phase 2: tbuf = Ys @ Wcs  (each thread: 8 rows x 4 cols)
    float acc2[8][4];
    #pragma unroll
    for (int i = 0; i < 8; i++)
        #pragma unroll
        for (int j = 0; j < 4; j++) acc2[i][j] = 0.f;

    for (int k = 0; k < 128; k += 2) {
        float2 a2[8];
        #pragma unroll
        for (int i = 0; i < 8; i++)
            a2[i] = __half22float2(*(const __half2*)&Ys[tr * 8 + i][k]);
        float4 b0 = *(const float4*)&Wcs[k][tc * 4];
        float4 b1v = *(const float4*)&Wcs[k + 1][tc * 4];
        #pragma unroll
        for (int i = 0; i < 8; i++) {
            acc2[i][0] += a2[i].x * b0.x + a2[i].y * b1v.x;
            acc2[i][1] += a2[i].x * b0.y + a2[i].y * b1v.y;
            acc2[i][2] += a2[i].x * b0.z + a2[i].y * b1v.z;
            acc2[i][3] += a2[i].x * b0.w + a2[i].y * b1v.w;
        }
    }

    #pragma unroll
    for (int i = 0; i < 8; i++) {
        int row = blk0 + tr * 8 + i;
        if (row < M) {
            *(__half2*)&C[(size_t)row * OD + tc * 4]     = __floats2half2_rn(acc2[i][0], acc2[i][1]);
            *(__half2*)&C[(size_t)row * OD + tc * 4 + 2] = __floats2half2_rn(acc2[i][2], acc2[i][3]);
        }
    }
}

// ---------------- fold W2@Wf, b2@Wf+bf ----------------
__global__ void fold_kernel(const float* __restrict__ W2, const float* __restrict__ Wf,
                            const float* __restrict__ b2, const float* __restrict__ bf,
                            float* __restrict__ Wc, float* __restrict__ bc) {
    int idx = blockIdx.x * 256 + threadIdx.x;
    if (idx < FD * OD) {
        int i = idx / OD, j = idx % OD;
        float s = 0.f;
        for (int k = 0; k < FD; k++) s += W2[i * FD + k] * Wf[k * OD + j];
        Wc[idx] = s;
    }
    if (idx < OD) {
        float s = bf[idx];
        for (int k = 0; k < FD; k++) s += b2[k] * Wf[k * OD + idx];
        bc[idx] = s;
    }
}

// ---------------- launch ----------------
extern "C" void kernel_launch(void* const* d_in, const int* in_sizes, int n_in,
                              void* d_out, int out_size, void* d_ws, size_t ws_size,
                              hipStream_t stream) {
    const float* in_feat = (const float*)d_in[0];
    const int*   src     = (const int*)d_in[1];
    const int*   dst     = (const int*)d_in[2];
    const float* W1      = (const float*)d_in[3];
    const float* b1      = (const float*)d_in[4];
    const float* W2      = (const float*)d_in[5];
    const float* b2      = (const float*)d_in[6];
    const float* Wf      = (const float*)d_in[7];
    const float* bf      = (const float*)d_in[8];
    float* out = (float*)d_out;

    const int N = in_sizes[0] / FD;        // 50000
    const int E = in_sizes[1];             // 1600000
    const int NR = (N + RN - 1) / RN;      // 196 (<= NRMAX)
    const int CS = (E + CHUNKS - 1) / CHUNKS;

    char* ws = (char*)d_ws;
    size_t off = 0;
    auto alloc = [&](size_t bytes) -> void* {
        void* p = ws + off;
        off += (bytes + 255) / 256 * 256;
        return p;
    };
    // cnt_src (6.4 MB) dead after rout; tbuf (N*OD*2 = 6.4 MB half) aliases it.
    int*    cnt_src = (int*)alloc((size_t)KC * N * 4);
    __half* tbuf    = (__half*)cnt_src;
    int*    epack   = (int*)alloc((size_t)E * 4);        // dead after region_sort
    float*  r_out   = (float*)alloc((size_t)N * 4);
    float*  r_in    = (float*)alloc((size_t)N * 4);
    int*    hist_g  = (int*)alloc((size_t)CHUNKS * NR * 4);
    int*    cursor  = (int*)alloc((size_t)CHUNKS * NR * 4);
    int*    rstart  = (int*)alloc((size_t)(NR + 1) * 4);
    int*    csrc    = (int*)alloc((size_t)E * 4);
    int*    row_start = (int*)alloc((size_t)(N + 1) * 4);
    float*  z1      = (float*)alloc((size_t)N * FD * 4);
    __half* Xs      = (__half*)alloc((size_t)N * FD * 2);
    float*  Wc      = (float*)alloc((size_t)FD * OD * 4);
    float*  bc      = (float*)alloc((size_t)OD * 4);
    (void)ws_size; (void)n_in; (void)out_size;

    const int gN = (N + 255) / 256;

    // exact dst-sort: region partition (pass 1) + per-region counting sort (pass 2).
    // pass 1 also builds the privatized src histogram (deg_out).
    zero_kernel<<<(KC * N + 255) / 256, 256, 0, stream>>>(cnt_src, KC * N);
    region_hist_kernel<<<CHUNKS, 256, 0, stream>>>(dst, hist_g, E, NR, CS);
    region_scan_kernel<<<1, 1024, 0, stream>>>(hist_g, rstart, NR, E);
    region_cursor_kernel<<<(NR + 255) / 256, 256, 0, stream>>>(hist_g, rstart, cursor, NR);
    partition_kernel<<<CHUNKS, 512, 0, stream>>>(src, dst, cursor, epack, cnt_src, E, NR, CS, N);
    region_sort_kernel<<<NR, 1024, 0, stream>>>(epack, rstart, csrc, row_start, r_in, N, NR, E);
    rout_kernel<<<gN, 256, 0, stream>>>(cnt_src, r_out, N);

    // fold final two linear layers
    fold_kernel<<<(FD * OD + 255) / 256, 256, 0, stream>>>(W2, Wf, b2, bf, Wc, bc);

    // layer 1: Xs = half(r_out*x) ; z1 = r_in*Agg(Xs)
    prescale_kernel<<<(N * 32 + 255) / 256, 256, 0, stream>>>(in_feat, r_out, Xs, N * 32);
    agg128_kernel<<<(N + 3) / 4, 256, 0, stream>>>(Xs, r_in, row_start, csrc, z1, N);

    // fused: tbuf = half( (relu(z1@W1+b1)*r_out) @ Wc )
    gemm_fused_kernel<<<(N + 127) / 128, 256, 0, stream>>>(z1, W1, b1, r_out, Wc, tbuf, N);

    // final: out = r_in*Agg(tbuf) + bc
    agg64_kernel<<<(N + 3) / 4, 256, 0, stream>>>(tbuf, r_in, row_start, csrc, bc, out, N);
}